// Round 4
// baseline (242.100 us; speedup 1.0000x reference)
//
#include <hip/hip_runtime.h>

// GRAPE step collapse: all steps rotate about X, so the scan == one rotation by
// Theta = sum(a_k) * (DT/2).
//   out_real0 = c*r0 + s*i1    out_imag0 = c*i0 - s*r1
//   out_real1 = c*r1 + s*i0    out_imag1 = c*i1 - s*r0
// Output layout: [real0 | real1 | imag0 | imag1], each segment B floats.
//
// The rotation couples segments only in PAIRS (R3 insight, kept):
//   pair h=0: (r0, i1) -> (out0, out3)
//   pair h=1: (r1, i0) -> (out1, out2)
// R4 structure: pair-split + PERSISTENT grid-stride (2048 blocks = 8 blk/CU =
// 32 waves/CU resident, G11 — the structure LN-class kernels use to hit ~82%
// of HBM BW) + unroll-2 (two independent 16B-chunk positions in flight/wave).
// h = blockIdx.x & 1: with round-robin block->XCD dispatch, each XCD's L2
// sees only one pair's 2R+2W streams.
// History: R0 4-stream one-shot 81us; R1 +nt 87 (reverted); R2 persistent
// 8-wide 4-stream 87; R3 pair-split one-shot 79 (other dispatches faster).

typedef float f4 __attribute__((ext_vector_type(4)));

__global__ __launch_bounds__(256) void grape_kernel(
    const float* __restrict__ amps, int nsteps,
    const float* __restrict__ sreal, const float* __restrict__ simag,
    float* __restrict__ out, long long B) {
    // Theta is wave-uniform; a handful of scalar cached loads, negligible.
    float theta = 0.0f;
    for (int k = 0; k < nsteps; ++k) theta += amps[k];
    theta *= (1.0f / (float)nsteps) * 0.5f;  // DT/2 with GATE_TIME=1.0
    const float c = cosf(theta);
    const float s = sinf(theta);

    const int h = (int)(blockIdx.x & 1);
    const long long tph = ((long long)(gridDim.x >> 1)) * blockDim.x;  // threads/half
    const long long t0 =
        ((long long)(blockIdx.x >> 1)) * blockDim.x + threadIdx.x;

    const float* __restrict__ x = sreal + (long long)h * B;        // r0 or r1
    const float* __restrict__ y = simag + (long long)(1 - h) * B;  // i1 or i0
    float* __restrict__ outr = out + (long long)h * B;             // out0/out1
    float* __restrict__ outi = out + (long long)(3 - h) * B;       // out3/out2

    const long long nv = B >> 2;  // f4 chunks per stream
    long long v = t0;

    // unroll-2 grid-stride: 4 loads (2 indep chunk positions) issued before
    // any store -> 2 round-trips in flight per wave.
    for (; v + tph < nv; v += 2 * tph) {
        const long long j0 = v << 2;
        const long long j1 = (v + tph) << 2;
        const f4 x0 = *(const f4*)(x + j0);
        const f4 y0 = *(const f4*)(y + j0);
        const f4 x1 = *(const f4*)(x + j1);
        const f4 y1 = *(const f4*)(y + j1);
        *(f4*)(outr + j0) = c * x0 + s * y0;
        *(f4*)(outi + j0) = c * y0 - s * x0;
        *(f4*)(outr + j1) = c * x1 + s * y1;
        *(f4*)(outi + j1) = c * y1 - s * x1;
    }
    for (; v < nv; v += tph) {
        const long long j = v << 2;
        const f4 xv = *(const f4*)(x + j);
        const f4 yv = *(const f4*)(y + j);
        *(f4*)(outr + j) = c * xv + s * yv;
        *(f4*)(outi + j) = c * yv - s * xv;
    }

    // scalar tail (only if B % 4 != 0); each half covers its own pair.
    for (long long t = (nv << 2) + t0; t < B; t += tph) {
        const float xs = x[t], ys = y[t];
        outr[t] = c * xs + s * ys;
        outi[t] = c * ys - s * xs;
    }
}

extern "C" void kernel_launch(void* const* d_in, const int* in_sizes, int n_in,
                              void* d_out, int out_size, void* d_ws, size_t ws_size,
                              hipStream_t stream) {
    const float* amps  = (const float*)d_in[0];
    const float* sreal = (const float*)d_in[1];
    const float* simag = (const float*)d_in[2];
    float* out = (float*)d_out;

    int nsteps = in_sizes[0];
    long long B = (long long)in_sizes[1] / 2;  // state_real is [2, B]

    // Persistent: 2048 blocks x 256 thr = 8 blocks/CU = 32 waves/CU resident.
    // Grid must be even (parity encodes the pair index h).
    const int block = 256;
    const int grid = 2048;

    grape_kernel<<<grid, block, 0, stream>>>(amps, nsteps, sreal, simag, out, B);
}

// Round 5
// 236.434 us; speedup vs baseline: 1.0240x; 1.0240x over previous
//
#include <hip/hip_runtime.h>

// GRAPE step collapse: all steps rotate about X, so the scan == one rotation by
// Theta = sum(a_k) * (DT/2).
//   out_real0 = c*r0 + s*i1    out_imag0 = c*i0 - s*r1
//   out_real1 = c*r1 + s*i0    out_imag1 = c*i1 - s*r0
// Output layout: [real0 | real1 | imag0 | imag1], each segment B floats.
//
// Pair decoupling (R3, best structure at ~79us):
//   pair h=0: (r0, i1) -> (out0, out3)
//   pair h=1: (r1, i0) -> (out1, out2)
// Each half-grid is a pure 2-load/2-store stream.
//
// R5 single change: STREAMING STORES via inline asm `global_store_dwordx4
// ... sc0 sc1 nt`. Working set = input 128.125 MiB + output 128 MiB =
// 256.1 MiB, straddling the 256 MiB MALL exactly -> output write-allocation
// evicts half the input every iteration (FETCH pinned at 65.5 MB across R0-R4).
// R1's __builtin_nontemporal_store (nt bit only) was inert; the sc0/sc1 SCOPE
// bits are the untested allocation-policy lever on gfx95x. If output stops
// allocating in MALL, input becomes fully LLC-resident -> FETCH ~0.
// History: R0 4-stream one-shot 81us; R1 +nt-builtin 87; R2 persistent 8-wide
// 87; R3 pair-split one-shot 79; R4 pair-split persistent unroll2 82.

typedef float f4 __attribute__((ext_vector_type(4)));

__device__ __forceinline__ void store_stream(float* p, f4 v) {
    asm volatile("global_store_dwordx4 %0, %1, off sc0 sc1 nt"
                 :: "v"(p), "v"(v)
                 : "memory");
}

__global__ __launch_bounds__(256) void grape_kernel(
    const float* __restrict__ amps, int nsteps,
    const float* __restrict__ sreal, const float* __restrict__ simag,
    float* __restrict__ out, long long B, long long blocks_per_half) {
    // Theta is wave-uniform; a handful of scalar cached loads, negligible.
    float theta = 0.0f;
    for (int k = 0; k < nsteps; ++k) theta += amps[k];
    theta *= (1.0f / (float)nsteps) * 0.5f;  // DT/2 with GATE_TIME=1.0
    const float c = cosf(theta);
    const float s = sinf(theta);

    const long long h = (blockIdx.x >= blocks_per_half) ? 1 : 0;
    const long long v = ((long long)blockIdx.x - h * blocks_per_half) * blockDim.x
                        + threadIdx.x;
    const long long j = v * 4;

    const float* __restrict__ x = sreal + h * B;        // r0 or r1
    const float* __restrict__ y = simag + (1 - h) * B;  // i1 or i0
    float* __restrict__ outr = out + h * B;             // out0 or out1
    float* __restrict__ outi = out + (3 - h) * B;       // out3 or out2

    if (j + 3 < B) {
        const f4 xv = *(const f4*)(x + j);
        const f4 yv = *(const f4*)(y + j);
        store_stream(outr + j, c * xv + s * yv);
        store_stream(outi + j, c * yv - s * xv);
    } else if (j < B) {
        for (long long t = j; t < B; ++t) {
            const float xs = x[t], ys = y[t];
            outr[t] = c * xs + s * ys;
            outi[t] = c * ys - s * xs;
        }
    }
}

extern "C" void kernel_launch(void* const* d_in, const int* in_sizes, int n_in,
                              void* d_out, int out_size, void* d_ws, size_t ws_size,
                              hipStream_t stream) {
    const float* amps  = (const float*)d_in[0];
    const float* sreal = (const float*)d_in[1];
    const float* simag = (const float*)d_in[2];
    float* out = (float*)d_out;

    int nsteps = in_sizes[0];
    long long B = (long long)in_sizes[1] / 2;  // state_real is [2, B]

    const int block = 256;
    long long nv = (B + 3) / 4;                       // f4 chunks per half
    long long blocks_per_half = (nv + block - 1) / block;
    long long grid = 2 * blocks_per_half;             // one-shot (R0/R3 > R2/R4)

    grape_kernel<<<(dim3)(unsigned)grid, block, 0, stream>>>(
        amps, nsteps, sreal, simag, out, B, blocks_per_half);
}

// Round 6
// 225.706 us; speedup vs baseline: 1.0726x; 1.0475x over previous
//
#include <hip/hip_runtime.h>

// GRAPE step collapse: all steps rotate about X, so the scan == one rotation by
// Theta = sum(a_k) * (DT/2).
//   out_real0 = c*r0 + s*i1    out_imag0 = c*i0 - s*r1
//   out_real1 = c*r1 + s*i0    out_imag1 = c*i1 - s*r0
// Output layout: [real0 | real1 | imag0 | imag1], each segment B floats.
//
// Pair decoupling (R3, best structure at ~79us):
//   pair h=0: (r0, i1) -> (out0, out3)
//   pair h=1: (r1, i0) -> (out1, out2)
// Each half-grid is a pure 2-load/2-store stream.
//
// R6 single change: NON-TEMPORAL LOADS (__builtin_nontemporal_load).
// Diagnostic for the dirty-LLC eviction theory: harness poison fill (512 MiB
// @6.7 TB/s) leaves the 256 MiB LLC fully dirty; our kernel's 256 MiB of
// allocations (128 read-fill + 128 write-alloc) each force a victim
// writeback -> hidden HBM write stream ~= the 2.5x gap to copy speed.
// nt loads = input never allocates -> only the 128 MiB output allocates
// (fits LLC). Signal: FETCH 65.5 -> ~131 MB if the hint is live.
// History: R0 4-stream one-shot 81us; R1 nt-store 87; R2 persistent 8-wide
// 87; R3 pair-split one-shot 79; R4 pair-split persistent unroll2 82;
// R5 sc0sc1nt-store 80 (FETCH/WRITE byte-identical R0-R5).

typedef float f4 __attribute__((ext_vector_type(4)));

__global__ __launch_bounds__(256) void grape_kernel(
    const float* __restrict__ amps, int nsteps,
    const float* __restrict__ sreal, const float* __restrict__ simag,
    float* __restrict__ out, long long B, long long blocks_per_half) {
    // Theta is wave-uniform; a handful of scalar cached loads, negligible.
    float theta = 0.0f;
    for (int k = 0; k < nsteps; ++k) theta += amps[k];
    theta *= (1.0f / (float)nsteps) * 0.5f;  // DT/2 with GATE_TIME=1.0
    const float c = cosf(theta);
    const float s = sinf(theta);

    const long long h = (blockIdx.x >= blocks_per_half) ? 1 : 0;
    const long long v = ((long long)blockIdx.x - h * blocks_per_half) * blockDim.x
                        + threadIdx.x;
    const long long j = v * 4;

    const float* __restrict__ x = sreal + h * B;        // r0 or r1
    const float* __restrict__ y = simag + (1 - h) * B;  // i1 or i0
    float* __restrict__ outr = out + h * B;             // out0 or out1
    float* __restrict__ outi = out + (3 - h) * B;       // out3 or out2

    if (j + 3 < B) {
        const f4 xv = __builtin_nontemporal_load((const f4*)(x + j));
        const f4 yv = __builtin_nontemporal_load((const f4*)(y + j));
        *(f4*)(outr + j) = c * xv + s * yv;
        *(f4*)(outi + j) = c * yv - s * xv;
    } else if (j < B) {
        for (long long t = j; t < B; ++t) {
            const float xs = x[t], ys = y[t];
            outr[t] = c * xs + s * ys;
            outi[t] = c * ys - s * xs;
        }
    }
}

extern "C" void kernel_launch(void* const* d_in, const int* in_sizes, int n_in,
                              void* d_out, int out_size, void* d_ws, size_t ws_size,
                              hipStream_t stream) {
    const float* amps  = (const float*)d_in[0];
    const float* sreal = (const float*)d_in[1];
    const float* simag = (const float*)d_in[2];
    float* out = (float*)d_out;

    int nsteps = in_sizes[0];
    long long B = (long long)in_sizes[1] / 2;  // state_real is [2, B]

    const int block = 256;
    long long nv = (B + 3) / 4;                       // f4 chunks per half
    long long blocks_per_half = (nv + block - 1) / block;
    long long grid = 2 * blocks_per_half;             // one-shot (best: R3)

    grape_kernel<<<(dim3)(unsigned)grid, block, 0, stream>>>(
        amps, nsteps, sreal, simag, out, B, blocks_per_half);
}